// Round 19
// baseline (1595.467 us; speedup 1.0000x reference)
//
#include <hip/hip_runtime.h>
#include <hip/hip_cooperative_groups.h>
#include <math.h>

namespace cg = cooperative_groups;

#define BS 32
#define N 2048
#define ROWS (BS * N)
#define IN 128
#define HID 64
#define K_CAP 80
#define EPS 1e-5f
#define ALPHA 0.1f

typedef float fx4 __attribute__((ext_vector_type(4)));

__device__ __forceinline__ float bf2f(unsigned short u) {
    union { float f; unsigned v; } x; x.v = ((unsigned)u) << 16; return x.f;
}
__device__ __forceinline__ unsigned short f2bf(float f) {
    union { float f; unsigned v; } x; x.f = f;
    unsigned r = x.v + 0x7fff + ((x.v >> 16) & 1);
    return (unsigned short)(r >> 16);
}

// betas: float(log(1/(i+1)+1)) precomputed
__device__ __constant__ float BETAS[4] = {0.6931471806f, 0.4054651081f,
                                          0.2876820724f, 0.2231435513f};

// ===========================================================================
// MEGA KERNEL (cooperative): build+proj | sync | 4x (layer | sync)
// - launch_bounds(256,8): <=64 VGPR -> 8 blocks/CU -> 2048 blocks co-resident
// - LDS: one 16 KB buffer (proj x-stage in phase 0; ss[16][64] in layers)
// - threadfence + grid.sync between dependent phases (cross-XCD visibility)
// ===========================================================================
__global__ __launch_bounds__(256, 8) void k_mega(
    const float* __restrict__ adj, const float* __restrict__ x,
    const float* __restrict__ proj_w, const float* __restrict__ proj_b,
    const float* __restrict__ ln_g, const float* __restrict__ ln_b,
    const float* __restrict__ conv_w,
    const float* __restrict__ head_w, const float* __restrict__ head_b,
    float* __restrict__ h, unsigned short* __restrict__ za,
    unsigned short* __restrict__ zb,
    float* __restrict__ dinv, int* __restrict__ cnt, int* __restrict__ ell,
    float* __restrict__ out, int nb) {
    __shared__ float smem[32 * 128];  // 16 KB
    cg::grid_group grid = cg::this_grid();
    int tx = threadIdx.x;
    int lane = tx & 63, wid = tx >> 6;
    int bid = blockIdx.x;

    // ---------------- phase 0a: build ELL + dinv (grid-stride) ------------
    for (int g4 = bid; g4 < ROWS / 4; g4 += nb) {
        int row = g4 * 4 + wid;
        const fx4* arow = (const fx4*)(adj + (size_t)row * N);
        int* erow = ell + (unsigned)row * K_CAP;
        int base = 0;
#pragma unroll
        for (int it = 0; it < N / 256; it++) {
            fx4 f = __builtin_nontemporal_load(&arow[it * 64 + lane]);
#pragma unroll
            for (int k = 0; k < 4; k++) {
                float v = f[k];
                unsigned long long m = __ballot(v != 0.0f);
                if (v != 0.0f) {
                    int pos = base + __popcll(m & ((1ull << lane) - 1ull));
                    if (pos < K_CAP) erow[pos] = it * 256 + lane * 4 + k;
                }
                base += __popcll(m);
            }
        }
        if (lane == 0) {
            cnt[row]  = base < K_CAP ? base : K_CAP;
            dinv[row] = rsqrtf((float)base + 1.0f);
        }
    }

    // ---------------- phase 0b: proj + LN0 -> h, za (grid-stride) ---------
    // LDS-light: x staged (32 rows x 128 = 16 KB), W from global (L1).
    for (int g32 = bid; g32 < ROWS / 32; g32 += nb) {
        int rowbase = g32 * 32;
        __syncthreads();  // protect smem reuse across iterations/phases
        for (int i = tx; i < 1024; i += 256) {
            int r = i >> 5, f4 = i & 31;
            float4 v = *(const float4*)(x + (size_t)(rowbase + r) * IN + f4 * 4);
            *(float4*)&smem[r * IN + f4 * 4] = v;
        }
        __syncthreads();
        float acc[8];
#pragma unroll
        for (int r = 0; r < 8; r++) acc[r] = proj_b[lane];
#pragma unroll 4
        for (int k = 0; k < IN; k += 4) {
            float w0 = proj_w[(unsigned)((k + 0) * HID + lane)];
            float w1 = proj_w[(unsigned)((k + 1) * HID + lane)];
            float w2 = proj_w[(unsigned)((k + 2) * HID + lane)];
            float w3 = proj_w[(unsigned)((k + 3) * HID + lane)];
#pragma unroll
            for (int r = 0; r < 8; r++) {
                float4 sk = *(const float4*)&smem[(wid * 8 + r) * IN + k];
                acc[r] += sk.x * w0 + sk.y * w1 + sk.z * w2 + sk.w * w3;
            }
        }
#pragma unroll
        for (int r = 0; r < 8; r++) {
            int row = rowbase + wid * 8 + r;
            unsigned idx = (unsigned)(row * HID + lane);
            float hv = acc[r];
            h[idx] = hv;
            float sum = hv;
            for (int o = 32; o >= 1; o >>= 1) sum += __shfl_xor(sum, o);
            float mu = sum * (1.0f / 64.0f);
            float d  = hv - mu;
            float vs = d * d;
            for (int o = 32; o >= 1; o >>= 1) vs += __shfl_xor(vs, o);
            float rv = rsqrtf(vs * (1.0f / 64.0f) + EPS);
            float zz = d * rv * ln_g[lane] + ln_b[lane];
            za[idx] = f2bf(zz > 0.0f ? zz : 0.0f);
        }
    }

    __threadfence();
    grid.sync();

    // ---------------- phases 1..4: layers ---------------------------------
    unsigned short* zi_p = za;
    unsigned short* zo_p = zb;
    int p = lane & 15, q = lane >> 4;
    float (*ss)[HID] = (float (*)[HID])smem;  // 16x64 per chunk (4 KB used)

#pragma unroll 1
    for (int li = 0; li < 4; li++) {
        float beta = BETAS[li];
        int is_last = (li == 3);
        int gi = (li + 1) < 3 ? (li + 1) : 3;
        const float* w      = conv_w + (unsigned)li * HID * HID;
        const float* g_next = ln_g + gi * HID;
        const float* b_next = ln_b + gi * HID;

#pragma unroll 1
        for (int cl = bid; cl < ROWS / 16; cl += nb) {
            int c = ((cl & 7) << 9) + (cl >> 3);   // bijective XCD swizzle
            int row0 = c * 16 + wid * 4;
            int jbase = row0 & ~(N - 1);
            const ushort4* zb4 = (const ushort4*)zi_p + (unsigned)jbase * 16u;
            const ushort4* zr4 = (const ushort4*)zi_p;

            int nn[4];
            unsigned mypk[4];
#pragma unroll
            for (int rr = 0; rr < 4; rr++) {
                int row = row0 + rr;
                nn[rr] = cnt[row];
                mypk[rr] = 0u;
                if (lane < nn[rr]) {
                    int j = ell[(unsigned)row * K_CAP + lane];
                    union { float f; unsigned v; } u;
                    u.f = dinv[jbase + j];
                    mypk[rr] = (u.v & 0xFFFFF800u) | (unsigned)j;
                }
            }
            int ntm = 0;
#pragma unroll
            for (int rr = 0; rr < 4; rr++) {
                int nm = nn[rr] < 64 ? nn[rr] : 64;
                nm = (nm + 3) & ~3;
                ntm = nm > ntm ? nm : ntm;
            }

            float4 acc[4];
#pragma unroll
            for (int rr = 0; rr < 4; rr++) acc[rr] = make_float4(0.f, 0.f, 0.f, 0.f);
            for (int t = q; t < ntm; t += 4) {
#pragma unroll
                for (int rr = 0; rr < 4; rr++) {
                    unsigned v = (unsigned)__shfl((int)mypk[rr], t);
                    int j = (int)(v & 0x7FFu);
                    union { unsigned u; float f; } wu; wu.u = v & 0xFFFFF800u;
                    float wj = wu.f;
                    ushort4 zu = zb4[(unsigned)(j * 16 + p)];
                    acc[rr].x += wj * bf2f(zu.x); acc[rr].y += wj * bf2f(zu.y);
                    acc[rr].z += wj * bf2f(zu.z); acc[rr].w += wj * bf2f(zu.w);
                }
            }
#pragma unroll
            for (int rr = 0; rr < 4; rr++) {
                for (int t = 64 + q; t < nn[rr]; t += 4) {
                    int   j  = jbase + ell[(unsigned)(row0 + rr) * K_CAP + t];
                    float wj = dinv[j];
                    ushort4 zu = zr4[(unsigned)(j * 16 + p)];
                    acc[rr].x += wj * bf2f(zu.x); acc[rr].y += wj * bf2f(zu.y);
                    acc[rr].z += wj * bf2f(zu.z); acc[rr].w += wj * bf2f(zu.w);
                }
            }

            const float c1 = 1.0f - ALPHA;
#pragma unroll
            for (int rr = 0; rr < 4; rr++) {
                float4 a = acc[rr];
                a.x += __shfl_xor(a.x, 16); a.y += __shfl_xor(a.y, 16);
                a.z += __shfl_xor(a.z, 16); a.w += __shfl_xor(a.w, 16);
                a.x += __shfl_xor(a.x, 32); a.y += __shfl_xor(a.y, 32);
                a.z += __shfl_xor(a.z, 32); a.w += __shfl_xor(a.w, 32);
                int row = row0 + rr;
                float dd = dinv[row];
                ushort4 zu = zr4[(unsigned)(row * 16 + p)];
                float4 zi = make_float4(bf2f(zu.x), bf2f(zu.y), bf2f(zu.z), bf2f(zu.w));
                float4 s4;
                s4.x = c1 * dd * (a.x + dd * zi.x) + ALPHA * zi.x;
                s4.y = c1 * dd * (a.y + dd * zi.y) + ALPHA * zi.y;
                s4.z = c1 * dd * (a.z + dd * zi.z) + ALPHA * zi.z;
                s4.w = c1 * dd * (a.w + dd * zi.w) + ALPHA * zi.w;
                if (q == 0) *(float4*)&ss[wid * 4 + rr][4 * p] = s4;
            }
            // ss rows are wave-private; lgkmcnt orders write->read in-wave.

            float mv[4] = {0.f, 0.f, 0.f, 0.f};
#pragma unroll 4
            for (int k = 0; k < HID; k += 4) {
                float w0 = w[(unsigned)((k + 0) * HID + lane)];
                float w1 = w[(unsigned)((k + 1) * HID + lane)];
                float w2 = w[(unsigned)((k + 2) * HID + lane)];
                float w3 = w[(unsigned)((k + 3) * HID + lane)];
#pragma unroll
                for (int rr = 0; rr < 4; rr++) {
                    float4 sk = *(const float4*)&ss[wid * 4 + rr][k];
                    mv[rr] += sk.x * w0 + sk.y * w1 + sk.z * w2 + sk.w * w3;
                }
            }

#pragma unroll
            for (int rr = 0; rr < 4; rr++) {
                int row = row0 + rr;
                float s_c = ss[wid * 4 + rr][lane];
                unsigned idx = (unsigned)(row * HID + lane);
                float hn = __builtin_nontemporal_load(h + idx) +
                           (1.0f - beta) * s_c + beta * mv[rr];
                if (!is_last) {
                    __builtin_nontemporal_store(hn, h + idx);
                    float sum = hn;
                    for (int o = 32; o >= 1; o >>= 1) sum += __shfl_xor(sum, o);
                    float mu = sum * (1.0f / 64.0f);
                    float d  = hn - mu;
                    float vs = d * d;
                    for (int o = 32; o >= 1; o >>= 1) vs += __shfl_xor(vs, o);
                    float rv = rsqrtf(vs * (1.0f / 64.0f) + EPS);
                    float zz = d * rv * g_next[lane] + b_next[lane];
                    zo_p[idx] = f2bf(zz > 0.0f ? zz : 0.0f);
                } else {
                    float v = hn * head_w[lane];
                    for (int o = 32; o >= 1; o >>= 1) v += __shfl_xor(v, o);
                    if (lane == 0) out[row] = v + head_b[0];
                }
            }
        }

        if (!is_last) {
            __threadfence();
            grid.sync();
            __threadfence();
        }
        unsigned short* t = zi_p; zi_p = zo_p; zo_p = t;
    }
}

// ===========================================================================
// FALLBACK kernels (r18 path) -- used only if cooperative launch errors.
// ===========================================================================
__global__ __launch_bounds__(256) void k_build(const float* __restrict__ adj,
                                               int* __restrict__ ell,
                                               int* __restrict__ cnt,
                                               float* __restrict__ dinv) {
    int lane = threadIdx.x & 63;
    int row  = blockIdx.x * 4 + (threadIdx.x >> 6);
    const fx4* arow = (const fx4*)(adj + (size_t)row * N);
    int* erow = ell + (size_t)row * K_CAP;
    int base = 0;
#pragma unroll
    for (int it = 0; it < N / 256; it++) {
        fx4 f = __builtin_nontemporal_load(&arow[it * 64 + lane]);
#pragma unroll
        for (int k = 0; k < 4; k++) {
            float v = f[k];
            unsigned long long m = __ballot(v != 0.0f);
            if (v != 0.0f) {
                int pos = base + __popcll(m & ((1ull << lane) - 1ull));
                if (pos < K_CAP) erow[pos] = it * 256 + lane * 4 + k;
            }
            base += __popcll(m);
        }
    }
    if (lane == 0) {
        cnt[row]  = base < K_CAP ? base : K_CAP;
        dinv[row] = rsqrtf((float)base + 1.0f);
    }
}

__global__ __launch_bounds__(256) void k_proj_ln(const float* __restrict__ x,
                                                 const float* __restrict__ w,
                                                 const float* __restrict__ b,
                                                 const float* __restrict__ g0,
                                                 const float* __restrict__ b0,
                                                 float* __restrict__ h,
                                                 unsigned short* __restrict__ z0) {
    __shared__ float sw[IN * HID];
    __shared__ float sx[4][IN];
    int tx = threadIdx.x;
    for (int i = tx; i < IN * HID; i += 256) sw[i] = w[i];
    int row0 = blockIdx.x * 4;
    if (tx < 128) {
        float4 v = *(const float4*)(x + (size_t)(row0 + (tx >> 5)) * IN + (tx & 31) * 4);
        *(float4*)&sx[tx >> 5][(tx & 31) * 4] = v;
    }
    __syncthreads();
    int c = tx & 63, r = tx >> 6;
    float acc = b[c];
#pragma unroll
    for (int k = 0; k < IN; k += 4) {
        float4 xa = *(const float4*)&sx[r][k];
        acc += xa.x * sw[(k + 0) * HID + c];
        acc += xa.y * sw[(k + 1) * HID + c];
        acc += xa.z * sw[(k + 2) * HID + c];
        acc += xa.w * sw[(k + 3) * HID + c];
    }
    size_t idx = (size_t)(row0 + r) * HID + c;
    h[idx] = acc;
    float sum = acc;
    for (int o = 32; o >= 1; o >>= 1) sum += __shfl_xor(sum, o);
    float mu = sum * (1.0f / 64.0f);
    float d  = acc - mu;
    float vs = d * d;
    for (int o = 32; o >= 1; o >>= 1) vs += __shfl_xor(vs, o);
    float rr = rsqrtf(vs * (1.0f / 64.0f) + EPS);
    float zz = d * rr * g0[c] + b0[c];
    z0[idx] = f2bf(zz > 0.0f ? zz : 0.0f);
}

__global__ __launch_bounds__(256, 8) void k_layer(
    float* __restrict__ h, const unsigned short* __restrict__ z_in,
    unsigned short* __restrict__ z_out,
    const int* __restrict__ ell, const int* __restrict__ cnt,
    const float* __restrict__ dinv, const float* __restrict__ w,
    const float* __restrict__ g_next, const float* __restrict__ b_next,
    float beta, int is_last,
    const float* __restrict__ head_w, const float* __restrict__ head_b,
    float* __restrict__ out) {
    __shared__ float ss[16][HID];
    int tx = threadIdx.x;
    int lane = tx & 63, wid = tx >> 6;
    int p = lane & 15, q = lane >> 4;
    int bid = blockIdx.x;
    int swz = (bid & 7) * (int)(gridDim.x >> 3) + (bid >> 3);
    int row0 = swz * 16 + wid * 4;
    int jbase = row0 & ~(N - 1);
    const ushort4* zb4 = (const ushort4*)z_in + (unsigned)jbase * 16u;
    const ushort4* zr4 = (const ushort4*)z_in;

    int nn[4];
    unsigned mypk[4];
#pragma unroll
    for (int rr = 0; rr < 4; rr++) {
        int row = row0 + rr;
        nn[rr] = cnt[row];
        mypk[rr] = 0u;
        if (lane < nn[rr]) {
            int j = ell[(unsigned)row * K_CAP + lane];
            union { float f; unsigned v; } u;
            u.f = dinv[jbase + j];
            mypk[rr] = (u.v & 0xFFFFF800u) | (unsigned)j;
        }
    }
    int ntm = 0;
#pragma unroll
    for (int rr = 0; rr < 4; rr++) {
        int nm = nn[rr] < 64 ? nn[rr] : 64;
        nm = (nm + 3) & ~3;
        ntm = nm > ntm ? nm : ntm;
    }
    float4 acc[4];
#pragma unroll
    for (int rr = 0; rr < 4; rr++) acc[rr] = make_float4(0.f, 0.f, 0.f, 0.f);
    for (int t = q; t < ntm; t += 4) {
#pragma unroll
        for (int rr = 0; rr < 4; rr++) {
            unsigned v = (unsigned)__shfl((int)mypk[rr], t);
            int j = (int)(v & 0x7FFu);
            union { unsigned u; float f; } wu; wu.u = v & 0xFFFFF800u;
            float wj = wu.f;
            ushort4 zu = zb4[(unsigned)(j * 16 + p)];
            acc[rr].x += wj * bf2f(zu.x); acc[rr].y += wj * bf2f(zu.y);
            acc[rr].z += wj * bf2f(zu.z); acc[rr].w += wj * bf2f(zu.w);
        }
    }
#pragma unroll
    for (int rr = 0; rr < 4; rr++) {
        for (int t = 64 + q; t < nn[rr]; t += 4) {
            int   j  = jbase + ell[(unsigned)(row0 + rr) * K_CAP + t];
            float wj = dinv[j];
            ushort4 zu = zr4[(unsigned)(j * 16 + p)];
            acc[rr].x += wj * bf2f(zu.x); acc[rr].y += wj * bf2f(zu.y);
            acc[rr].z += wj * bf2f(zu.z); acc[rr].w += wj * bf2f(zu.w);
        }
    }
    const float c1 = 1.0f - ALPHA;
#pragma unroll
    for (int rr = 0; rr < 4; rr++) {
        float4 a = acc[rr];
        a.x += __shfl_xor(a.x, 16); a.y += __shfl_xor(a.y, 16);
        a.z += __shfl_xor(a.z, 16); a.w += __shfl_xor(a.w, 16);
        a.x += __shfl_xor(a.x, 32); a.y += __shfl_xor(a.y, 32);
        a.z += __shfl_xor(a.z, 32); a.w += __shfl_xor(a.w, 32);
        int row = row0 + rr;
        float dd = dinv[row];
        ushort4 zu = zr4[(unsigned)(row * 16 + p)];
        float4 zi = make_float4(bf2f(zu.x), bf2f(zu.y), bf2f(zu.z), bf2f(zu.w));
        float4 s4;
        s4.x = c1 * dd * (a.x + dd * zi.x) + ALPHA * zi.x;
        s4.y = c1 * dd * (a.y + dd * zi.y) + ALPHA * zi.y;
        s4.z = c1 * dd * (a.z + dd * zi.z) + ALPHA * zi.z;
        s4.w = c1 * dd * (a.w + dd * zi.w) + ALPHA * zi.w;
        if (q == 0) *(float4*)&ss[wid * 4 + rr][4 * p] = s4;
    }
    float mv[4] = {0.f, 0.f, 0.f, 0.f};
#pragma unroll 4
    for (int k = 0; k < HID; k += 4) {
        float w0 = w[(unsigned)((k + 0) * HID + lane)];
        float w1 = w[(unsigned)((k + 1) * HID + lane)];
        float w2 = w[(unsigned)((k + 2) * HID + lane)];
        float w3 = w[(unsigned)((k + 3) * HID + lane)];
#pragma unroll
        for (int rr = 0; rr < 4; rr++) {
            float4 sk = *(const float4*)&ss[wid * 4 + rr][k];
            mv[rr] += sk.x * w0 + sk.y * w1 + sk.z * w2 + sk.w * w3;
        }
    }
#pragma unroll
    for (int rr = 0; rr < 4; rr++) {
        int row = row0 + rr;
        float s_c = ss[wid * 4 + rr][lane];
        unsigned idx = (unsigned)(row * HID + lane);
        float hn = __builtin_nontemporal_load(h + idx) +
                   (1.0f - beta) * s_c + beta * mv[rr];
        if (!is_last) {
            __builtin_nontemporal_store(hn, h + idx);
            float sum = hn;
            for (int o = 32; o >= 1; o >>= 1) sum += __shfl_xor(sum, o);
            float mu = sum * (1.0f / 64.0f);
            float d  = hn - mu;
            float vs = d * d;
            for (int o = 32; o >= 1; o >>= 1) vs += __shfl_xor(vs, o);
            float rv = rsqrtf(vs * (1.0f / 64.0f) + EPS);
            float zz = d * rv * g_next[lane] + b_next[lane];
            z_out[idx] = f2bf(zz > 0.0f ? zz : 0.0f);
        } else {
            float v = hn * head_w[lane];
            for (int o = 32; o >= 1; o >>= 1) v += __shfl_xor(v, o);
            if (lane == 0) out[row] = v + head_b[0];
        }
    }
}

extern "C" void kernel_launch(void* const* d_in, const int* in_sizes, int n_in,
                              void* d_out, int out_size, void* d_ws, size_t ws_size,
                              hipStream_t stream) {
    const float* x      = (const float*)d_in[0];
    const float* adj    = (const float*)d_in[1];
    const float* proj_w = (const float*)d_in[2];
    const float* proj_b = (const float*)d_in[3];
    const float* ln_g   = (const float*)d_in[4];
    const float* ln_b   = (const float*)d_in[5];
    const float* conv_w = (const float*)d_in[6];
    const float* head_w = (const float*)d_in[7];
    const float* head_b = (const float*)d_in[8];
    float* out = (float*)d_out;

    float* h  = (float*)d_ws;                        // ROWS*HID f32
    unsigned short* za = (unsigned short*)(h + (size_t)ROWS * HID);  // bf16
    unsigned short* zb = za + (size_t)ROWS * HID;                    // bf16
    float* dinv = (float*)(zb + (size_t)ROWS * HID); // ROWS
    int*   cnt  = (int*)(dinv + ROWS);               // ROWS
    int*   ell  = cnt + ROWS;                        // ROWS*K_CAP

    // co-residency-safe grid size for the cooperative launch
    int bpc = 0;
    if (hipOccupancyMaxActiveBlocksPerMultiprocessor(&bpc, k_mega, 256, 0)
            != hipSuccess || bpc < 1)
        bpc = 8;
    int nb = bpc * 256;
    if (nb > 2048) nb = 2048;

    void* args[] = {(void*)&adj, (void*)&x, (void*)&proj_w, (void*)&proj_b,
                    (void*)&ln_g, (void*)&ln_b, (void*)&conv_w,
                    (void*)&head_w, (void*)&head_b,
                    (void*)&h, (void*)&za, (void*)&zb,
                    (void*)&dinv, (void*)&cnt, (void*)&ell,
                    (void*)&out, (void*)&nb};
    hipError_t err = hipLaunchCooperativeKernel((void*)k_mega, dim3(nb), dim3(256),
                                                args, 0, stream);
    if (err == hipSuccess) return;

    // -------- fallback: r18 6-launch path --------
    dim3 blk(256);
    k_build<<<dim3(ROWS / 4), blk, 0, stream>>>(adj, ell, cnt, dinv);
    k_proj_ln<<<dim3(ROWS / 4), blk, 0, stream>>>(x, proj_w, proj_b, ln_g, ln_b, h, za);
    unsigned short* zin = za;
    unsigned short* zout = zb;
    for (int i = 0; i < 4; i++) {
        float beta = (float)log(1.0 / (double)(i + 1) + 1.0);
        int last = (i == 3);
        int gi = (i + 1) < 3 ? (i + 1) : 3;
        k_layer<<<dim3(ROWS / 16), blk, 0, stream>>>(h, zin, zout, ell, cnt, dinv,
                                                     conv_w + (size_t)i * HID * HID,
                                                     ln_g + gi * HID, ln_b + gi * HID,
                                                     beta, last, head_w, head_b, out);
        unsigned short* t = zin; zin = zout; zout = t;
    }
}

// Round 20
// 1236.048 us; speedup vs baseline: 1.2908x; 1.2908x over previous
//
#include <hip/hip_runtime.h>
#include <hip/hip_cooperative_groups.h>
#include <math.h>

namespace cg = cooperative_groups;

#define BS 32
#define N 2048
#define ROWS (BS * N)
#define IN 128
#define HID 64
#define K_CAP 80
#define EPS 1e-5f
#define ALPHA 0.1f

typedef float fx4 __attribute__((ext_vector_type(4)));

__device__ __forceinline__ float bf2f(unsigned short u) {
    union { float f; unsigned v; } x; x.v = ((unsigned)u) << 16; return x.f;
}
__device__ __forceinline__ unsigned short f2bf(float f) {
    union { float f; unsigned v; } x; x.f = f;
    unsigned r = x.v + 0x7fff + ((x.v >> 16) & 1);
    return (unsigned short)(r >> 16);
}

__device__ __constant__ float BETAS[4] = {0.6931471806f, 0.4054651081f,
                                          0.2876820724f, 0.2231435513f};

// ---------------------------------------------------------------------------
// Kernel 1: build ELL + dinv. Standalone (at its 536 MB HBM floor, ~91 us).
// r19 lesson: fusing this into the coop kernel spilled it to scratch (32
// VGPR, 213 GB/s). It stays a full-occupancy separate launch.
// ---------------------------------------------------------------------------
__global__ __launch_bounds__(256) void k_build(const float* __restrict__ adj,
                                               int* __restrict__ ell,
                                               int* __restrict__ cnt,
                                               float* __restrict__ dinv) {
    int lane = threadIdx.x & 63;
    int row  = blockIdx.x * 4 + (threadIdx.x >> 6);
    const fx4* arow = (const fx4*)(adj + (size_t)row * N);
    int* erow = ell + (size_t)row * K_CAP;
    int base = 0;
#pragma unroll
    for (int it = 0; it < N / 256; it++) {
        fx4 f = __builtin_nontemporal_load(&arow[it * 64 + lane]);
#pragma unroll
        for (int k = 0; k < 4; k++) {
            float v = f[k];
            unsigned long long m = __ballot(v != 0.0f);
            if (v != 0.0f) {
                int pos = base + __popcll(m & ((1ull << lane) - 1ull));
                if (pos < K_CAP) erow[pos] = it * 256 + lane * 4 + k;
            }
            base += __popcll(m);
        }
    }
    if (lane == 0) {
        cnt[row]  = base < K_CAP ? base : K_CAP;
        dinv[row] = rsqrtf((float)base + 1.0f);
    }
}

// ===========================================================================
// Coop kernel v2: proj+LN0 | sync | 4x (layer via atomic WORK QUEUE | sync)
//  - launch_bounds(256,6): ~85-VGPR budget -> NO spill (r19's failure mode),
//    6 blocks/CU co-resident.
//  - chunks pulled from qctr[li] (atomicAdd): perfect balance regardless of
//    nb; output values are block-assignment-independent -> deterministic.
//  - layer body byte-identical to r18's k_layer.
// ===========================================================================
__global__ __launch_bounds__(256, 6) void k_mega2(
    const float* __restrict__ x,
    const float* __restrict__ proj_w, const float* __restrict__ proj_b,
    const float* __restrict__ ln_g, const float* __restrict__ ln_b,
    const float* __restrict__ conv_w,
    const float* __restrict__ head_w, const float* __restrict__ head_b,
    float* __restrict__ h, unsigned short* __restrict__ za,
    unsigned short* __restrict__ zb,
    const float* __restrict__ dinv, const int* __restrict__ cnt,
    const int* __restrict__ ell, int* __restrict__ qctr,
    float* __restrict__ out, int nb) {
    __shared__ float smem[32 * 128];  // 16 KB (proj x-stage; layer ss)
    __shared__ int sChunk;
    cg::grid_group grid = cg::this_grid();
    int tx = threadIdx.x;
    int lane = tx & 63, wid = tx >> 6;
    int bid = blockIdx.x;

    // ---------------- phase 0: zero queue + proj + LN0 --------------------
    if (bid == 0 && tx < 8) qctr[tx] = 0;
    for (int g32 = bid; g32 < ROWS / 32; g32 += nb) {
        int rowbase = g32 * 32;
        __syncthreads();
        for (int i = tx; i < 1024; i += 256) {
            int r = i >> 5, f4 = i & 31;
            float4 v = *(const float4*)(x + (size_t)(rowbase + r) * IN + f4 * 4);
            *(float4*)&smem[r * IN + f4 * 4] = v;
        }
        __syncthreads();
        float acc[8];
#pragma unroll
        for (int r = 0; r < 8; r++) acc[r] = proj_b[lane];
#pragma unroll 4
        for (int k = 0; k < IN; k += 4) {
            float w0 = proj_w[(unsigned)((k + 0) * HID + lane)];
            float w1 = proj_w[(unsigned)((k + 1) * HID + lane)];
            float w2 = proj_w[(unsigned)((k + 2) * HID + lane)];
            float w3 = proj_w[(unsigned)((k + 3) * HID + lane)];
#pragma unroll
            for (int r = 0; r < 8; r++) {
                float4 sk = *(const float4*)&smem[(wid * 8 + r) * IN + k];
                acc[r] += sk.x * w0 + sk.y * w1 + sk.z * w2 + sk.w * w3;
            }
        }
#pragma unroll
        for (int r = 0; r < 8; r++) {
            int row = rowbase + wid * 8 + r;
            unsigned idx = (unsigned)(row * HID + lane);
            float hv = acc[r];
            h[idx] = hv;
            float sum = hv;
            for (int o = 32; o >= 1; o >>= 1) sum += __shfl_xor(sum, o);
            float mu = sum * (1.0f / 64.0f);
            float d  = hv - mu;
            float vs = d * d;
            for (int o = 32; o >= 1; o >>= 1) vs += __shfl_xor(vs, o);
            float rv = rsqrtf(vs * (1.0f / 64.0f) + EPS);
            float zz = d * rv * ln_g[lane] + ln_b[lane];
            za[idx] = f2bf(zz > 0.0f ? zz : 0.0f);
        }
    }

    __threadfence();
    grid.sync();

    // ---------------- phases 1..4: layers (work-queue balanced) -----------
    unsigned short* zi_p = za;
    unsigned short* zo_p = zb;
    int p = lane & 15, q = lane >> 4;
    float (*ss)[HID] = (float (*)[HID])smem;

#pragma unroll 1
    for (int li = 0; li < 4; li++) {
        float beta = BETAS[li];
        int is_last = (li == 3);
        int gi = (li + 1) < 3 ? (li + 1) : 3;
        const float* w      = conv_w + (unsigned)li * HID * HID;
        const float* g_next = ln_g + gi * HID;
        const float* b_next = ln_b + gi * HID;

        while (true) {
            __syncthreads();                       // protect sChunk reuse
            if (tx == 0) sChunk = atomicAdd(&qctr[li], 1);
            __syncthreads();
            int cl = sChunk;
            if (cl >= ROWS / 16) break;            // block-uniform exit

            int c = ((cl & 7) << 9) + (cl >> 3);   // bijective XCD swizzle
            int row0 = c * 16 + wid * 4;
            int jbase = row0 & ~(N - 1);
            const ushort4* zb4 = (const ushort4*)zi_p + (unsigned)jbase * 16u;
            const ushort4* zr4 = (const ushort4*)zi_p;

            int nn[4];
            unsigned mypk[4];
#pragma unroll
            for (int rr = 0; rr < 4; rr++) {
                int row = row0 + rr;
                nn[rr] = cnt[row];
                mypk[rr] = 0u;
                if (lane < nn[rr]) {
                    int j = ell[(unsigned)row * K_CAP + lane];
                    union { float f; unsigned v; } u;
                    u.f = dinv[jbase + j];
                    mypk[rr] = (u.v & 0xFFFFF800u) | (unsigned)j;
                }
            }
            int ntm = 0;
#pragma unroll
            for (int rr = 0; rr < 4; rr++) {
                int nm = nn[rr] < 64 ? nn[rr] : 64;
                nm = (nm + 3) & ~3;
                ntm = nm > ntm ? nm : ntm;
            }

            float4 acc[4];
#pragma unroll
            for (int rr = 0; rr < 4; rr++) acc[rr] = make_float4(0.f, 0.f, 0.f, 0.f);
            for (int t = q; t < ntm; t += 4) {
#pragma unroll
                for (int rr = 0; rr < 4; rr++) {
                    unsigned v = (unsigned)__shfl((int)mypk[rr], t);
                    int j = (int)(v & 0x7FFu);
                    union { unsigned u; float f; } wu; wu.u = v & 0xFFFFF800u;
                    float wj = wu.f;
                    ushort4 zu = zb4[(unsigned)(j * 16 + p)];
                    acc[rr].x += wj * bf2f(zu.x); acc[rr].y += wj * bf2f(zu.y);
                    acc[rr].z += wj * bf2f(zu.z); acc[rr].w += wj * bf2f(zu.w);
                }
            }
#pragma unroll
            for (int rr = 0; rr < 4; rr++) {
                for (int t = 64 + q; t < nn[rr]; t += 4) {
                    int   j  = jbase + ell[(unsigned)(row0 + rr) * K_CAP + t];
                    float wj = dinv[j];
                    ushort4 zu = zr4[(unsigned)(j * 16 + p)];
                    acc[rr].x += wj * bf2f(zu.x); acc[rr].y += wj * bf2f(zu.y);
                    acc[rr].z += wj * bf2f(zu.z); acc[rr].w += wj * bf2f(zu.w);
                }
            }

            const float c1 = 1.0f - ALPHA;
#pragma unroll
            for (int rr = 0; rr < 4; rr++) {
                float4 a = acc[rr];
                a.x += __shfl_xor(a.x, 16); a.y += __shfl_xor(a.y, 16);
                a.z += __shfl_xor(a.z, 16); a.w += __shfl_xor(a.w, 16);
                a.x += __shfl_xor(a.x, 32); a.y += __shfl_xor(a.y, 32);
                a.z += __shfl_xor(a.z, 32); a.w += __shfl_xor(a.w, 32);
                int row = row0 + rr;
                float dd = dinv[row];
                ushort4 zu = zr4[(unsigned)(row * 16 + p)];
                float4 zi = make_float4(bf2f(zu.x), bf2f(zu.y), bf2f(zu.z), bf2f(zu.w));
                float4 s4;
                s4.x = c1 * dd * (a.x + dd * zi.x) + ALPHA * zi.x;
                s4.y = c1 * dd * (a.y + dd * zi.y) + ALPHA * zi.y;
                s4.z = c1 * dd * (a.z + dd * zi.z) + ALPHA * zi.z;
                s4.w = c1 * dd * (a.w + dd * zi.w) + ALPHA * zi.w;
                if (q == 0) *(float4*)&ss[wid * 4 + rr][4 * p] = s4;
            }
            // ss rows wave-private; lgkmcnt orders in-wave write->read.

            float mv[4] = {0.f, 0.f, 0.f, 0.f};
#pragma unroll 4
            for (int k = 0; k < HID; k += 4) {
                float w0 = w[(unsigned)((k + 0) * HID + lane)];
                float w1 = w[(unsigned)((k + 1) * HID + lane)];
                float w2 = w[(unsigned)((k + 2) * HID + lane)];
                float w3 = w[(unsigned)((k + 3) * HID + lane)];
#pragma unroll
                for (int rr = 0; rr < 4; rr++) {
                    float4 sk = *(const float4*)&ss[wid * 4 + rr][k];
                    mv[rr] += sk.x * w0 + sk.y * w1 + sk.z * w2 + sk.w * w3;
                }
            }

#pragma unroll
            for (int rr = 0; rr < 4; rr++) {
                int row = row0 + rr;
                float s_c = ss[wid * 4 + rr][lane];
                unsigned idx = (unsigned)(row * HID + lane);
                float hn = __builtin_nontemporal_load(h + idx) +
                           (1.0f - beta) * s_c + beta * mv[rr];
                if (!is_last) {
                    __builtin_nontemporal_store(hn, h + idx);
                    float sum = hn;
                    for (int o = 32; o >= 1; o >>= 1) sum += __shfl_xor(sum, o);
                    float mu = sum * (1.0f / 64.0f);
                    float d  = hn - mu;
                    float vs = d * d;
                    for (int o = 32; o >= 1; o >>= 1) vs += __shfl_xor(vs, o);
                    float rv = rsqrtf(vs * (1.0f / 64.0f) + EPS);
                    float zz = d * rv * g_next[lane] + b_next[lane];
                    zo_p[idx] = f2bf(zz > 0.0f ? zz : 0.0f);
                } else {
                    float v = hn * head_w[lane];
                    for (int o = 32; o >= 1; o >>= 1) v += __shfl_xor(v, o);
                    if (lane == 0) out[row] = v + head_b[0];
                }
            }
        }

        if (!is_last) {
            __threadfence();
            grid.sync();
        }
        unsigned short* t = zi_p; zi_p = zo_p; zo_p = t;
    }
}

// ===========================================================================
// FALLBACK kernels (r18 path, measured 365 us) -- used if coop launch errors.
// ===========================================================================
__global__ __launch_bounds__(256) void k_proj_ln(const float* __restrict__ x,
                                                 const float* __restrict__ w,
                                                 const float* __restrict__ b,
                                                 const float* __restrict__ g0,
                                                 const float* __restrict__ b0,
                                                 float* __restrict__ h,
                                                 unsigned short* __restrict__ z0) {
    __shared__ float sw[IN * HID];
    __shared__ float sx[4][IN];
    int tx = threadIdx.x;
    for (int i = tx; i < IN * HID; i += 256) sw[i] = w[i];
    int row0 = blockIdx.x * 4;
    if (tx < 128) {
        float4 v = *(const float4*)(x + (size_t)(row0 + (tx >> 5)) * IN + (tx & 31) * 4);
        *(float4*)&sx[tx >> 5][(tx & 31) * 4] = v;
    }
    __syncthreads();
    int c = tx & 63, r = tx >> 6;
    float acc = b[c];
#pragma unroll
    for (int k = 0; k < IN; k += 4) {
        float4 xa = *(const float4*)&sx[r][k];
        acc += xa.x * sw[(k + 0) * HID + c];
        acc += xa.y * sw[(k + 1) * HID + c];
        acc += xa.z * sw[(k + 2) * HID + c];
        acc += xa.w * sw[(k + 3) * HID + c];
    }
    size_t idx = (size_t)(row0 + r) * HID + c;
    h[idx] = acc;
    float sum = acc;
    for (int o = 32; o >= 1; o >>= 1) sum += __shfl_xor(sum, o);
    float mu = sum * (1.0f / 64.0f);
    float d  = acc - mu;
    float vs = d * d;
    for (int o = 32; o >= 1; o >>= 1) vs += __shfl_xor(vs, o);
    float rr = rsqrtf(vs * (1.0f / 64.0f) + EPS);
    float zz = d * rr * g0[c] + b0[c];
    z0[idx] = f2bf(zz > 0.0f ? zz : 0.0f);
}

__global__ __launch_bounds__(256, 8) void k_layer(
    float* __restrict__ h, const unsigned short* __restrict__ z_in,
    unsigned short* __restrict__ z_out,
    const int* __restrict__ ell, const int* __restrict__ cnt,
    const float* __restrict__ dinv, const float* __restrict__ w,
    const float* __restrict__ g_next, const float* __restrict__ b_next,
    float beta, int is_last,
    const float* __restrict__ head_w, const float* __restrict__ head_b,
    float* __restrict__ out) {
    __shared__ float ss[16][HID];
    int tx = threadIdx.x;
    int lane = tx & 63, wid = tx >> 6;
    int p = lane & 15, q = lane >> 4;
    int bid = blockIdx.x;
    int swz = (bid & 7) * (int)(gridDim.x >> 3) + (bid >> 3);
    int row0 = swz * 16 + wid * 4;
    int jbase = row0 & ~(N - 1);
    const ushort4* zb4 = (const ushort4*)z_in + (unsigned)jbase * 16u;
    const ushort4* zr4 = (const ushort4*)z_in;

    int nn[4];
    unsigned mypk[4];
#pragma unroll
    for (int rr = 0; rr < 4; rr++) {
        int row = row0 + rr;
        nn[rr] = cnt[row];
        mypk[rr] = 0u;
        if (lane < nn[rr]) {
            int j = ell[(unsigned)row * K_CAP + lane];
            union { float f; unsigned v; } u;
            u.f = dinv[jbase + j];
            mypk[rr] = (u.v & 0xFFFFF800u) | (unsigned)j;
        }
    }
    int ntm = 0;
#pragma unroll
    for (int rr = 0; rr < 4; rr++) {
        int nm = nn[rr] < 64 ? nn[rr] : 64;
        nm = (nm + 3) & ~3;
        ntm = nm > ntm ? nm : ntm;
    }
    float4 acc[4];
#pragma unroll
    for (int rr = 0; rr < 4; rr++) acc[rr] = make_float4(0.f, 0.f, 0.f, 0.f);
    for (int t = q; t < ntm; t += 4) {
#pragma unroll
        for (int rr = 0; rr < 4; rr++) {
            unsigned v = (unsigned)__shfl((int)mypk[rr], t);
            int j = (int)(v & 0x7FFu);
            union { unsigned u; float f; } wu; wu.u = v & 0xFFFFF800u;
            float wj = wu.f;
            ushort4 zu = zb4[(unsigned)(j * 16 + p)];
            acc[rr].x += wj * bf2f(zu.x); acc[rr].y += wj * bf2f(zu.y);
            acc[rr].z += wj * bf2f(zu.z); acc[rr].w += wj * bf2f(zu.w);
        }
    }
#pragma unroll
    for (int rr = 0; rr < 4; rr++) {
        for (int t = 64 + q; t < nn[rr]; t += 4) {
            int   j  = jbase + ell[(unsigned)(row0 + rr) * K_CAP + t];
            float wj = dinv[j];
            ushort4 zu = zr4[(unsigned)(j * 16 + p)];
            acc[rr].x += wj * bf2f(zu.x); acc[rr].y += wj * bf2f(zu.y);
            acc[rr].z += wj * bf2f(zu.z); acc[rr].w += wj * bf2f(zu.w);
        }
    }
    const float c1 = 1.0f - ALPHA;
#pragma unroll
    for (int rr = 0; rr < 4; rr++) {
        float4 a = acc[rr];
        a.x += __shfl_xor(a.x, 16); a.y += __shfl_xor(a.y, 16);
        a.z += __shfl_xor(a.z, 16); a.w += __shfl_xor(a.w, 16);
        a.x += __shfl_xor(a.x, 32); a.y += __shfl_xor(a.y, 32);
        a.z += __shfl_xor(a.z, 32); a.w += __shfl_xor(a.w, 32);
        int row = row0 + rr;
        float dd = dinv[row];
        ushort4 zu = zr4[(unsigned)(row * 16 + p)];
        float4 zi = make_float4(bf2f(zu.x), bf2f(zu.y), bf2f(zu.z), bf2f(zu.w));
        float4 s4;
        s4.x = c1 * dd * (a.x + dd * zi.x) + ALPHA * zi.x;
        s4.y = c1 * dd * (a.y + dd * zi.y) + ALPHA * zi.y;
        s4.z = c1 * dd * (a.z + dd * zi.z) + ALPHA * zi.z;
        s4.w = c1 * dd * (a.w + dd * zi.w) + ALPHA * zi.w;
        if (q == 0) *(float4*)&ss[wid * 4 + rr][4 * p] = s4;
    }
    float mv[4] = {0.f, 0.f, 0.f, 0.f};
#pragma unroll 4
    for (int k = 0; k < HID; k += 4) {
        float w0 = w[(unsigned)((k + 0) * HID + lane)];
        float w1 = w[(unsigned)((k + 1) * HID + lane)];
        float w2 = w[(unsigned)((k + 2) * HID + lane)];
        float w3 = w[(unsigned)((k + 3) * HID + lane)];
#pragma unroll
        for (int rr = 0; rr < 4; rr++) {
            float4 sk = *(const float4*)&ss[wid * 4 + rr][k];
            mv[rr] += sk.x * w0 + sk.y * w1 + sk.z * w2 + sk.w * w3;
        }
    }
#pragma unroll
    for (int rr = 0; rr < 4; rr++) {
        int row = row0 + rr;
        float s_c = ss[wid * 4 + rr][lane];
        unsigned idx = (unsigned)(row * HID + lane);
        float hn = __builtin_nontemporal_load(h + idx) +
                   (1.0f - beta) * s_c + beta * mv[rr];
        if (!is_last) {
            __builtin_nontemporal_store(hn, h + idx);
            float sum = hn;
            for (int o = 32; o >= 1; o >>= 1) sum += __shfl_xor(sum, o);
            float mu = sum * (1.0f / 64.0f);
            float d  = hn - mu;
            float vs = d * d;
            for (int o = 32; o >= 1; o >>= 1) vs += __shfl_xor(vs, o);
            float rv = rsqrtf(vs * (1.0f / 64.0f) + EPS);
            float zz = d * rv * g_next[lane] + b_next[lane];
            z_out[idx] = f2bf(zz > 0.0f ? zz : 0.0f);
        } else {
            float v = hn * head_w[lane];
            for (int o = 32; o >= 1; o >>= 1) v += __shfl_xor(v, o);
            if (lane == 0) out[row] = v + head_b[0];
        }
    }
}

extern "C" void kernel_launch(void* const* d_in, const int* in_sizes, int n_in,
                              void* d_out, int out_size, void* d_ws, size_t ws_size,
                              hipStream_t stream) {
    const float* x      = (const float*)d_in[0];
    const float* adj    = (const float*)d_in[1];
    const float* proj_w = (const float*)d_in[2];
    const float* proj_b = (const float*)d_in[3];
    const float* ln_g   = (const float*)d_in[4];
    const float* ln_b   = (const float*)d_in[5];
    const float* conv_w = (const float*)d_in[6];
    const float* head_w = (const float*)d_in[7];
    const float* head_b = (const float*)d_in[8];
    float* out = (float*)d_out;

    float* h  = (float*)d_ws;                        // ROWS*HID f32
    unsigned short* za = (unsigned short*)(h + (size_t)ROWS * HID);  // bf16
    unsigned short* zb = za + (size_t)ROWS * HID;                    // bf16
    float* dinv = (float*)(zb + (size_t)ROWS * HID); // ROWS
    int*   cnt  = (int*)(dinv + ROWS);               // ROWS
    int*   ell  = cnt + ROWS;                        // ROWS*K_CAP
    int*   qctr = ell + (size_t)ROWS * K_CAP;        // 8 ints (work queue)

    dim3 blk(256);

    // build always standalone (at its HBM floor)
    k_build<<<dim3(ROWS / 4), blk, 0, stream>>>(adj, ell, cnt, dinv);

    // cooperative proj+layers+head
    int bpc = 0;
    if (hipOccupancyMaxActiveBlocksPerMultiprocessor(&bpc, k_mega2, 256, 0)
            != hipSuccess || bpc < 1)
        bpc = 6;
    if (bpc > 8) bpc = 8;
    int nb = bpc * 256;

    void* args[] = {(void*)&x, (void*)&proj_w, (void*)&proj_b,
                    (void*)&ln_g, (void*)&ln_b, (void*)&conv_w,
                    (void*)&head_w, (void*)&head_b,
                    (void*)&h, (void*)&za, (void*)&zb,
                    (void*)&dinv, (void*)&cnt, (void*)&ell,
                    (void*)&qctr, (void*)&out, (void*)&nb};
    hipError_t err = hipLaunchCooperativeKernel((void*)k_mega2, dim3(nb), dim3(256),
                                                args, 0, stream);
    if (err == hipSuccess) return;

    // -------- fallback: r18 path (365 us) --------
    k_proj_ln<<<dim3(ROWS / 4), blk, 0, stream>>>(x, proj_w, proj_b, ln_g, ln_b, h, za);
    unsigned short* zin = za;
    unsigned short* zout = zb;
    for (int i = 0; i < 4; i++) {
        float beta = (float)log(1.0 / (double)(i + 1) + 1.0);
        int last = (i == 3);
        int gi = (i + 1) < 3 ? (i + 1) : 3;
        k_layer<<<dim3(ROWS / 16), blk, 0, stream>>>(h, zin, zout, ell, cnt, dinv,
                                                     conv_w + (size_t)i * HID * HID,
                                                     ln_g + gi * HID, ln_b + gi * HID,
                                                     beta, last, head_w, head_b, out);
        unsigned short* t = zin; zin = zout; zout = t;
    }
}

// Round 21
// 387.689 us; speedup vs baseline: 4.1153x; 3.1883x over previous
//
#include <hip/hip_runtime.h>
#include <math.h>

#define BS 32
#define N 2048
#define ROWS (BS * N)
#define IN 128
#define HID 64
#define K_CAP 80
#define EPS 1e-5f
#define ALPHA 0.1f

typedef float fx4 __attribute__((ext_vector_type(4)));

__device__ __forceinline__ float bf2f(unsigned short u) {
    union { float f; unsigned v; } x; x.v = ((unsigned)u) << 16; return x.f;
}
__device__ __forceinline__ unsigned short f2bf(float f) {
    union { float f; unsigned v; } x; x.f = f;
    unsigned r = x.v + 0x7fff + ((x.v >> 16) & 1);  // round-to-nearest-even
    return (unsigned short)(r >> 16);
}

// ---------------------------------------------------------------------------
// Kernel 1: build ELL + dinv. (measured r10: ~91 us = 536 MB HBM floor)
// ---------------------------------------------------------------------------
__global__ __launch_bounds__(256) void k_build(const float* __restrict__ adj,
                                               int* __restrict__ ell,
                                               int* __restrict__ cnt,
                                               float* __restrict__ dinv) {
    int lane = threadIdx.x & 63;
    int row  = blockIdx.x * 4 + (threadIdx.x >> 6);
    const fx4* arow = (const fx4*)(adj + (size_t)row * N);
    int* erow = ell + (size_t)row * K_CAP;
    int base = 0;
#pragma unroll
    for (int it = 0; it < N / 256; it++) {
        fx4 f = __builtin_nontemporal_load(&arow[it * 64 + lane]);
#pragma unroll
        for (int k = 0; k < 4; k++) {
            float v = f[k];
            unsigned long long m = __ballot(v != 0.0f);
            if (v != 0.0f) {
                int pos = base + __popcll(m & ((1ull << lane) - 1ull));
                if (pos < K_CAP) erow[pos] = it * 256 + lane * 4 + k;
            }
            base += __popcll(m);
        }
    }
    if (lane == 0) {
        cnt[row]  = base < K_CAP ? base : K_CAP;
        dinv[row] = rsqrtf((float)base + 1.0f);
    }
}

// ---------------------------------------------------------------------------
// Kernel 2: h = x @ proj_w + proj_b, fused with layer-0 LN+ReLU -> z0 (bf16).
// ---------------------------------------------------------------------------
__global__ __launch_bounds__(256) void k_proj_ln(const float* __restrict__ x,
                                                 const float* __restrict__ w,
                                                 const float* __restrict__ b,
                                                 const float* __restrict__ g0,
                                                 const float* __restrict__ b0,
                                                 float* __restrict__ h,
                                                 unsigned short* __restrict__ z0) {
    __shared__ float sw[IN * HID];
    __shared__ float sx[4][IN];
    int tx = threadIdx.x;
    for (int i = tx; i < IN * HID; i += 256) sw[i] = w[i];
    int row0 = blockIdx.x * 4;
    if (tx < 128) {
        float4 v = *(const float4*)(x + (size_t)(row0 + (tx >> 5)) * IN + (tx & 31) * 4);
        *(float4*)&sx[tx >> 5][(tx & 31) * 4] = v;
    }
    __syncthreads();
    int c = tx & 63, r = tx >> 6;
    float acc = b[c];
#pragma unroll
    for (int k = 0; k < IN; k += 4) {
        float4 xa = *(const float4*)&sx[r][k];
        acc += xa.x * sw[(k + 0) * HID + c];
        acc += xa.y * sw[(k + 1) * HID + c];
        acc += xa.z * sw[(k + 2) * HID + c];
        acc += xa.w * sw[(k + 3) * HID + c];
    }
    size_t idx = (size_t)(row0 + r) * HID + c;
    h[idx] = acc;
    float sum = acc;
    for (int o = 32; o >= 1; o >>= 1) sum += __shfl_xor(sum, o);
    float mu = sum * (1.0f / 64.0f);
    float d  = acc - mu;
    float vs = d * d;
    for (int o = 32; o >= 1; o >>= 1) vs += __shfl_xor(vs, o);
    float rr = rsqrtf(vs * (1.0f / 64.0f) + EPS);
    float zz = d * rr * g0[c] + b0[c];
    z0[idx] = f2bf(zz > 0.0f ? zz : 0.0f);
}

// ---------------------------------------------------------------------------
// Kernel 3 (per layer). r18 body (365 us total, session best) + ONE change:
// per-row wave-UNIFORM trip bound in the gather. nn[rr] is wave-uniform, so
// `t < ntot[rr]` is a scalar branch (no divergence); rows that are done skip
// their shfl+load+fma entirely (~25% of gather issue slots were padding to
// the 4-row max). Every executed __shfl still has all 64 lanes active.
// Coop fusion (r19/r20) is abandoned: the fused body spills to scratch.
// ---------------------------------------------------------------------------
__global__ __launch_bounds__(256, 8) void k_layer(
    float* __restrict__ h, const unsigned short* __restrict__ z_in,
    unsigned short* __restrict__ z_out,
    const int* __restrict__ ell, const int* __restrict__ cnt,
    const float* __restrict__ dinv, const float* __restrict__ w,
    const float* __restrict__ g_next, const float* __restrict__ b_next,
    float beta, int is_last,
    const float* __restrict__ head_w, const float* __restrict__ head_b,
    float* __restrict__ out) {
    __shared__ float ss[16][HID];
    int tx = threadIdx.x;
    int lane = tx & 63, wid = tx >> 6;
    int p = lane & 15, q = lane >> 4;
    int bid = blockIdx.x;
    int swz = (bid & 7) * (int)(gridDim.x >> 3) + (bid >> 3);
    int row0 = swz * 16 + wid * 4;
    int jbase = row0 & ~(N - 1);
    const ushort4* zb4 = (const ushort4*)z_in + (unsigned)jbase * 16u;
    const ushort4* zr4 = (const ushort4*)z_in;

    int nn[4], ntot[4];
    unsigned mypk[4];
#pragma unroll
    for (int rr = 0; rr < 4; rr++) {
        int row = row0 + rr;
        nn[rr] = cnt[row];
        mypk[rr] = 0u;
        if (lane < nn[rr]) {
            int j = ell[(unsigned)row * K_CAP + lane];
            union { float f; unsigned v; } u;
            u.f = dinv[jbase + j];
            mypk[rr] = (u.v & 0xFFFFF800u) | (unsigned)j;
        }
    }
    int ntm = 0;
#pragma unroll
    for (int rr = 0; rr < 4; rr++) {
        int nm = nn[rr] < 64 ? nn[rr] : 64;
        ntot[rr] = (nm + 3) & ~3;            // per-row, wave-uniform
        ntm = ntot[rr] > ntm ? ntot[rr] : ntm;
    }

    float4 acc[4];
#pragma unroll
    for (int rr = 0; rr < 4; rr++) acc[rr] = make_float4(0.f, 0.f, 0.f, 0.f);
    for (int t = q; t < ntm; t += 4) {
#pragma unroll
        for (int rr = 0; rr < 4; rr++) {
            if (t < ntot[rr]) {              // wave-uniform scalar branch
                unsigned v = (unsigned)__shfl((int)mypk[rr], t);  // 64 lanes
                int j = (int)(v & 0x7FFu);
                union { unsigned u; float f; } wu; wu.u = v & 0xFFFFF800u;
                float wj = wu.f;             // +0.0 for padded slots
                ushort4 zu = zb4[(unsigned)(j * 16 + p)];
                acc[rr].x += wj * bf2f(zu.x); acc[rr].y += wj * bf2f(zu.y);
                acc[rr].z += wj * bf2f(zu.z); acc[rr].w += wj * bf2f(zu.w);
            }
        }
    }
#pragma unroll
    for (int rr = 0; rr < 4; rr++) {          // rare deg>64 tail, no shfl
        for (int t = 64 + q; t < nn[rr]; t += 4) {
            int   j  = jbase + ell[(unsigned)(row0 + rr) * K_CAP + t];
            float wj = dinv[j];
            ushort4 zu = zr4[(unsigned)(j * 16 + p)];
            acc[rr].x += wj * bf2f(zu.x); acc[rr].y += wj * bf2f(zu.y);
            acc[rr].z += wj * bf2f(zu.z); acc[rr].w += wj * bf2f(zu.w);
        }
    }

    const float c1 = 1.0f - ALPHA;
#pragma unroll
    for (int rr = 0; rr < 4; rr++) {
        float4 a = acc[rr];
        a.x += __shfl_xor(a.x, 16); a.y += __shfl_xor(a.y, 16);
        a.z += __shfl_xor(a.z, 16); a.w += __shfl_xor(a.w, 16);
        a.x += __shfl_xor(a.x, 32); a.y += __shfl_xor(a.y, 32);
        a.z += __shfl_xor(a.z, 32); a.w += __shfl_xor(a.w, 32);
        int row = row0 + rr;
        float dd = dinv[row];
        ushort4 zu = zr4[(unsigned)(row * 16 + p)];
        float4 zi = make_float4(bf2f(zu.x), bf2f(zu.y), bf2f(zu.z), bf2f(zu.w));
        float4 s4;
        s4.x = c1 * dd * (a.x + dd * zi.x) + ALPHA * zi.x;
        s4.y = c1 * dd * (a.y + dd * zi.y) + ALPHA * zi.y;
        s4.z = c1 * dd * (a.z + dd * zi.z) + ALPHA * zi.z;
        s4.w = c1 * dd * (a.w + dd * zi.w) + ALPHA * zi.w;
        if (q == 0) *(float4*)&ss[wid * 4 + rr][4 * p] = s4;
    }
    // ss rows are wave-private; lgkmcnt orders in-wave write->read.

    float mv[4] = {0.f, 0.f, 0.f, 0.f};
#pragma unroll 4
    for (int k = 0; k < HID; k += 4) {
        float w0 = w[(unsigned)((k + 0) * HID + lane)];
        float w1 = w[(unsigned)((k + 1) * HID + lane)];
        float w2 = w[(unsigned)((k + 2) * HID + lane)];
        float w3 = w[(unsigned)((k + 3) * HID + lane)];
#pragma unroll
        for (int rr = 0; rr < 4; rr++) {
            float4 sk = *(const float4*)&ss[wid * 4 + rr][k];
            mv[rr] += sk.x * w0 + sk.y * w1 + sk.z * w2 + sk.w * w3;
        }
    }

#pragma unroll
    for (int rr = 0; rr < 4; rr++) {
        int row = row0 + rr;
        float s_c = ss[wid * 4 + rr][lane];
        unsigned idx = (unsigned)(row * HID + lane);
        float hn = __builtin_nontemporal_load(h + idx) +
                   (1.0f - beta) * s_c + beta * mv[rr];
        if (!is_last) {
            __builtin_nontemporal_store(hn, h + idx);
            float sum = hn;
            for (int o = 32; o >= 1; o >>= 1) sum += __shfl_xor(sum, o);
            float mu = sum * (1.0f / 64.0f);
            float d  = hn - mu;
            float vs = d * d;
            for (int o = 32; o >= 1; o >>= 1) vs += __shfl_xor(vs, o);
            float rv = rsqrtf(vs * (1.0f / 64.0f) + EPS);
            float zz = d * rv * g_next[lane] + b_next[lane];
            z_out[idx] = f2bf(zz > 0.0f ? zz : 0.0f);
        } else {
            float v = hn * head_w[lane];
            for (int o = 32; o >= 1; o >>= 1) v += __shfl_xor(v, o);
            if (lane == 0) out[row] = v + head_b[0];
        }
    }
}

extern "C" void kernel_launch(void* const* d_in, const int* in_sizes, int n_in,
                              void* d_out, int out_size, void* d_ws, size_t ws_size,
                              hipStream_t stream) {
    const float* x      = (const float*)d_in[0];
    const float* adj    = (const float*)d_in[1];
    const float* proj_w = (const float*)d_in[2];
    const float* proj_b = (const float*)d_in[3];
    const float* ln_g   = (const float*)d_in[4];
    const float* ln_b   = (const float*)d_in[5];
    const float* conv_w = (const float*)d_in[6];
    const float* head_w = (const float*)d_in[7];
    const float* head_b = (const float*)d_in[8];
    float* out = (float*)d_out;

    float* h  = (float*)d_ws;                        // ROWS*HID f32
    unsigned short* za = (unsigned short*)(h + (size_t)ROWS * HID);  // bf16
    unsigned short* zb = za + (size_t)ROWS * HID;                    // bf16
    float* dinv = (float*)(zb + (size_t)ROWS * HID); // ROWS
    int*   cnt  = (int*)(dinv + ROWS);               // ROWS
    int*   ell  = cnt + ROWS;                        // ROWS*K_CAP

    dim3 blk(256);

    k_build<<<dim3(ROWS / 4), blk, 0, stream>>>(adj, ell, cnt, dinv);
    k_proj_ln<<<dim3(ROWS / 4), blk, 0, stream>>>(x, proj_w, proj_b, ln_g, ln_b, h, za);

    unsigned short* zin = za;
    unsigned short* zout = zb;
    for (int i = 0; i < 4; i++) {
        float beta = (float)log(1.0 / (double)(i + 1) + 1.0);
        int last = (i == 3);
        int gi = (i + 1) < 3 ? (i + 1) : 3;
        k_layer<<<dim3(ROWS / 16), blk, 0, stream>>>(h, zin, zout, ell, cnt, dinv,
                                                     conv_w + (size_t)i * HID * HID,
                                                     ln_g + gi * HID, ln_b + gi * HID,
                                                     beta, last, head_w, head_b, out);
        unsigned short* t = zin; zin = zout; zout = t;
    }
}

// Round 22
// 374.299 us; speedup vs baseline: 4.2626x; 1.0358x over previous
//
#include <hip/hip_runtime.h>
#include <math.h>

#define BS 32
#define N 2048
#define ROWS (BS * N)
#define IN 128
#define HID 64
#define K_CAP 80
#define EPS 1e-5f
#define ALPHA 0.1f

typedef float fx4 __attribute__((ext_vector_type(4)));

__device__ __forceinline__ float bf2f(unsigned short u) {
    union { float f; unsigned v; } x; x.v = ((unsigned)u) << 16; return x.f;
}
__device__ __forceinline__ unsigned short f2bf(float f) {
    union { float f; unsigned v; } x; x.f = f;
    unsigned r = x.v + 0x7fff + ((x.v >> 16) & 1);  // round-to-nearest-even
    return (unsigned short)(r >> 16);
}

// ---------------------------------------------------------------------------
// Kernel 1: build ELL + dinv (phase A, ~91 us = 536 MB HBM floor) FUSED with
// proj+LN0 (phase B). The two phases are mutually independent (both read
// only inputs), so no sync is needed between them -- this deletes one
// ~10 us launch gap and lets proj compute hide under build's HBM tail.
// Unlike r19/r20's mega-kernel, this 2-phase body is small: no spill.
// ---------------------------------------------------------------------------
__global__ __launch_bounds__(256) void k_build_proj(
    const float* __restrict__ adj, const float* __restrict__ x,
    const float* __restrict__ pw, const float* __restrict__ pb,
    const float* __restrict__ g0, const float* __restrict__ b0,
    int* __restrict__ ell, int* __restrict__ cnt, float* __restrict__ dinv,
    float* __restrict__ h, unsigned short* __restrict__ z0) {
    __shared__ float sw[IN * HID];
    __shared__ float sx[4][IN];
    int tx = threadIdx.x;
    int lane = tx & 63, wid = tx >> 6;
    int row0 = blockIdx.x * 4;

    // ---- phase A: build (each wave owns one row) ----
    {
        int row = row0 + wid;
        const fx4* arow = (const fx4*)(adj + (size_t)row * N);
        int* erow = ell + (size_t)row * K_CAP;
        int base = 0;
#pragma unroll
        for (int it = 0; it < N / 256; it++) {
            fx4 f = __builtin_nontemporal_load(&arow[it * 64 + lane]);
#pragma unroll
            for (int k = 0; k < 4; k++) {
                float v = f[k];
                unsigned long long m = __ballot(v != 0.0f);
                if (v != 0.0f) {
                    int pos = base + __popcll(m & ((1ull << lane) - 1ull));
                    if (pos < K_CAP) erow[pos] = it * 256 + lane * 4 + k;
                }
                base += __popcll(m);
            }
        }
        if (lane == 0) {
            cnt[row]  = base < K_CAP ? base : K_CAP;
            dinv[row] = rsqrtf((float)base + 1.0f);
        }
    }

    // ---- phase B: proj + LN0 (independent of phase A; no fence needed) ----
    for (int i = tx; i < IN * HID; i += 256) sw[i] = pw[i];
    if (tx < 128) {
        float4 v = *(const float4*)(x + (size_t)(row0 + (tx >> 5)) * IN + (tx & 31) * 4);
        *(float4*)&sx[tx >> 5][(tx & 31) * 4] = v;
    }
    __syncthreads();
    float acc = pb[lane];
#pragma unroll
    for (int k = 0; k < IN; k += 4) {
        float4 xa = *(const float4*)&sx[wid][k];
        acc += xa.x * sw[(k + 0) * HID + lane];
        acc += xa.y * sw[(k + 1) * HID + lane];
        acc += xa.z * sw[(k + 2) * HID + lane];
        acc += xa.w * sw[(k + 3) * HID + lane];
    }
    size_t idx = (size_t)(row0 + wid) * HID + lane;
    h[idx] = acc;
    float sum = acc;
    for (int o = 32; o >= 1; o >>= 1) sum += __shfl_xor(sum, o);
    float mu = sum * (1.0f / 64.0f);
    float d  = acc - mu;
    float vs = d * d;
    for (int o = 32; o >= 1; o >>= 1) vs += __shfl_xor(vs, o);
    float rr = rsqrtf(vs * (1.0f / 64.0f) + EPS);
    float zz = d * rr * g0[lane] + b0[lane];
    z0[idx] = f2bf(zz > 0.0f ? zz : 0.0f);
}

// ---------------------------------------------------------------------------
// Kernel 3 (per layer). EXACT r18 body (measured 364.7 us total — session
// best). r21's per-row skip regressed (branchy inner loop broke load
// clauses); branch-free padded gather restored.
// ---------------------------------------------------------------------------
__global__ __launch_bounds__(256, 8) void k_layer(
    float* __restrict__ h, const unsigned short* __restrict__ z_in,
    unsigned short* __restrict__ z_out,
    const int* __restrict__ ell, const int* __restrict__ cnt,
    const float* __restrict__ dinv, const float* __restrict__ w,
    const float* __restrict__ g_next, const float* __restrict__ b_next,
    float beta, int is_last,
    const float* __restrict__ head_w, const float* __restrict__ head_b,
    float* __restrict__ out) {
    __shared__ float ss[16][HID];
    int tx = threadIdx.x;
    int lane = tx & 63, wid = tx >> 6;
    int p = lane & 15, q = lane >> 4;
    int bid = blockIdx.x;
    int swz = (bid & 7) * (int)(gridDim.x >> 3) + (bid >> 3);
    int row0 = swz * 16 + wid * 4;
    int jbase = row0 & ~(N - 1);
    const ushort4* zb4 = (const ushort4*)z_in + (unsigned)jbase * 16u;
    const ushort4* zr4 = (const ushort4*)z_in;

    int nn[4];
    unsigned mypk[4];
#pragma unroll
    for (int rr = 0; rr < 4; rr++) {
        int row = row0 + rr;
        nn[rr] = cnt[row];
        mypk[rr] = 0u;
        if (lane < nn[rr]) {
            int j = ell[(unsigned)row * K_CAP + lane];
            union { float f; unsigned v; } u;
            u.f = dinv[jbase + j];
            mypk[rr] = (u.v & 0xFFFFF800u) | (unsigned)j;
        }
    }
    int ntm = 0;
#pragma unroll
    for (int rr = 0; rr < 4; rr++) {
        int nm = nn[rr] < 64 ? nn[rr] : 64;
        nm = (nm + 3) & ~3;
        ntm = nm > ntm ? nm : ntm;
    }
    float4 acc[4];
#pragma unroll
    for (int rr = 0; rr < 4; rr++) acc[rr] = make_float4(0.f, 0.f, 0.f, 0.f);
    for (int t = q; t < ntm; t += 4) {
#pragma unroll
        for (int rr = 0; rr < 4; rr++) {
            unsigned v = (unsigned)__shfl((int)mypk[rr], t);
            int j = (int)(v & 0x7FFu);
            union { unsigned u; float f; } wu; wu.u = v & 0xFFFFF800u;
            float wj = wu.f;
            ushort4 zu = zb4[(unsigned)(j * 16 + p)];
            acc[rr].x += wj * bf2f(zu.x); acc[rr].y += wj * bf2f(zu.y);
            acc[rr].z += wj * bf2f(zu.z); acc[rr].w += wj * bf2f(zu.w);
        }
    }
#pragma unroll
    for (int rr = 0; rr < 4; rr++) {
        for (int t = 64 + q; t < nn[rr]; t += 4) {
            int   j  = jbase + ell[(unsigned)(row0 + rr) * K_CAP + t];
            float wj = dinv[j];
            ushort4 zu = zr4[(unsigned)(j * 16 + p)];
            acc[rr].x += wj * bf2f(zu.x); acc[rr].y += wj * bf2f(zu.y);
            acc[rr].z += wj * bf2f(zu.z); acc[rr].w += wj * bf2f(zu.w);
        }
    }
    const float c1 = 1.0f - ALPHA;
#pragma unroll
    for (int rr = 0; rr < 4; rr++) {
        float4 a = acc[rr];
        a.x += __shfl_xor(a.x, 16); a.y += __shfl_xor(a.y, 16);
        a.z += __shfl_xor(a.z, 16); a.w += __shfl_xor(a.w, 16);
        a.x += __shfl_xor(a.x, 32); a.y += __shfl_xor(a.y, 32);
        a.z += __shfl_xor(a.z, 32); a.w += __shfl_xor(a.w, 32);
        int row = row0 + rr;
        float dd = dinv[row];
        ushort4 zu = zr4[(unsigned)(row * 16 + p)];
        float4 zi = make_float4(bf2f(zu.x), bf2f(zu.y), bf2f(zu.z), bf2f(zu.w));
        float4 s4;
        s4.x = c1 * dd * (a.x + dd * zi.x) + ALPHA * zi.x;
        s4.y = c1 * dd * (a.y + dd * zi.y) + ALPHA * zi.y;
        s4.z = c1 * dd * (a.z + dd * zi.z) + ALPHA * zi.z;
        s4.w = c1 * dd * (a.w + dd * zi.w) + ALPHA * zi.w;
        if (q == 0) *(float4*)&ss[wid * 4 + rr][4 * p] = s4;
    }
    float mv[4] = {0.f, 0.f, 0.f, 0.f};
#pragma unroll 4
    for (int k = 0; k < HID; k += 4) {
        float w0 = w[(unsigned)((k + 0) * HID + lane)];
        float w1 = w[(unsigned)((k + 1) * HID + lane)];
        float w2 = w[(unsigned)((k + 2) * HID + lane)];
        float w3 = w[(unsigned)((k + 3) * HID + lane)];
#pragma unroll
        for (int rr = 0; rr < 4; rr++) {
            float4 sk = *(const float4*)&ss[wid * 4 + rr][k];
            mv[rr] += sk.x * w0 + sk.y * w1 + sk.z * w2 + sk.w * w3;
        }
    }
#pragma unroll
    for (int rr = 0; rr < 4; rr++) {
        int row = row0 + rr;
        float s_c = ss[wid * 4 + rr][lane];
        unsigned idx = (unsigned)(row * HID + lane);
        float hn = __builtin_nontemporal_load(h + idx) +
                   (1.0f - beta) * s_c + beta * mv[rr];
        if (!is_last) {
            __builtin_nontemporal_store(hn, h + idx);
            float sum = hn;
            for (int o = 32; o >= 1; o >>= 1) sum += __shfl_xor(sum, o);
            float mu = sum * (1.0f / 64.0f);
            float d  = hn - mu;
            float vs = d * d;
            for (int o = 32; o >= 1; o >>= 1) vs += __shfl_xor(vs, o);
            float rv = rsqrtf(vs * (1.0f / 64.0f) + EPS);
            float zz = d * rv * g_next[lane] + b_next[lane];
            z_out[idx] = f2bf(zz > 0.0f ? zz : 0.0f);
        } else {
            float v = hn * head_w[lane];
            for (int o = 32; o >= 1; o >>= 1) v += __shfl_xor(v, o);
            if (lane == 0) out[row] = v + head_b[0];
        }
    }
}

extern "C" void kernel_launch(void* const* d_in, const int* in_sizes, int n_in,
                              void* d_out, int out_size, void* d_ws, size_t ws_size,
                              hipStream_t stream) {
    const float* x      = (const float*)d_in[0];
    const float* adj    = (const float*)d_in[1];
    const float* proj_w = (const float*)d_in[2];
    const float* proj_b = (const float*)d_in[3];
    const float* ln_g   = (const float*)d_in[4];
    const float* ln_b   = (const float*)d_in[5];
    const float* conv_w = (const float*)d_in[6];
    const float* head_w = (const float*)d_in[7];
    const float* head_b = (const float*)d_in[8];
    float* out = (float*)d_out;

    float* h  = (float*)d_ws;                        // ROWS*HID f32
    unsigned short* za = (unsigned short*)(h + (size_t)ROWS * HID);  // bf16
    unsigned short* zb = za + (size_t)ROWS * HID;                    // bf16
    float* dinv = (float*)(zb + (size_t)ROWS * HID); // ROWS
    int*   cnt  = (int*)(dinv + ROWS);               // ROWS
    int*   ell  = cnt + ROWS;                        // ROWS*K_CAP

    dim3 blk(256);

    k_build_proj<<<dim3(ROWS / 4), blk, 0, stream>>>(adj, x, proj_w, proj_b,
                                                     ln_g, ln_b,
                                                     ell, cnt, dinv, h, za);

    unsigned short* zin = za;
    unsigned short* zout = zb;
    for (int i = 0; i < 4; i++) {
        float beta = (float)log(1.0 / (double)(i + 1) + 1.0);
        int last = (i == 3);
        int gi = (i + 1) < 3 ? (i + 1) : 3;
        k_layer<<<dim3(ROWS / 16), blk, 0, stream>>>(h, zin, zout, ell, cnt, dinv,
                                                     conv_w + (size_t)i * HID * HID,
                                                     ln_g + gi * HID, ln_b + gi * HID,
                                                     beta, last, head_w, head_b, out);
        unsigned short* t = zin; zin = zout; zout = t;
    }
}

// Round 23
// 364.329 us; speedup vs baseline: 4.3792x; 1.0274x over previous
//
#include <hip/hip_runtime.h>
#include <math.h>

#define BS 32
#define N 2048
#define ROWS (BS * N)
#define IN 128
#define HID 64
#define K_CAP 80
#define EPS 1e-5f
#define ALPHA 0.1f

typedef float fx4 __attribute__((ext_vector_type(4)));

__device__ __forceinline__ float bf2f(unsigned short u) {
    union { float f; unsigned v; } x; x.v = ((unsigned)u) << 16; return x.f;
}
__device__ __forceinline__ unsigned short f2bf(float f) {
    union { float f; unsigned v; } x; x.f = f;
    unsigned r = x.v + 0x7fff + ((x.v >> 16) & 1);  // round-to-nearest-even
    return (unsigned short)(r >> 16);
}

// ---------------------------------------------------------------------------
// Kernel 1: build ELL + dinv. Standalone, LDS-free, full occupancy.
// (measured r10: ~91 us = 536 MB HBM floor; r22 showed fusing proj in costs
// ~10 us via the LDS occupancy cap on this HBM-streaming phase.)
// ---------------------------------------------------------------------------
__global__ __launch_bounds__(256) void k_build(const float* __restrict__ adj,
                                               int* __restrict__ ell,
                                               int* __restrict__ cnt,
                                               float* __restrict__ dinv) {
    int lane = threadIdx.x & 63;
    int row  = blockIdx.x * 4 + (threadIdx.x >> 6);
    const fx4* arow = (const fx4*)(adj + (size_t)row * N);
    int* erow = ell + (size_t)row * K_CAP;
    int base = 0;
#pragma unroll
    for (int it = 0; it < N / 256; it++) {
        fx4 f = __builtin_nontemporal_load(&arow[it * 64 + lane]);
#pragma unroll
        for (int k = 0; k < 4; k++) {
            float v = f[k];
            unsigned long long m = __ballot(v != 0.0f);
            if (v != 0.0f) {
                int pos = base + __popcll(m & ((1ull << lane) - 1ull));
                if (pos < K_CAP) erow[pos] = it * 256 + lane * 4 + k;
            }
            base += __popcll(m);
        }
    }
    if (lane == 0) {
        cnt[row]  = base < K_CAP ? base : K_CAP;
        dinv[row] = rsqrtf((float)base + 1.0f);
    }
}

// ---------------------------------------------------------------------------
// Kernel 2: h = x @ proj_w + proj_b, fused with layer-0 LN+ReLU -> z0 (bf16).
// ---------------------------------------------------------------------------
__global__ __launch_bounds__(256) void k_proj_ln(const float* __restrict__ x,
                                                 const float* __restrict__ w,
                                                 const float* __restrict__ b,
                                                 const float* __restrict__ g0,
                                                 const float* __restrict__ b0,
                                                 float* __restrict__ h,
                                                 unsigned short* __restrict__ z0) {
    __shared__ float sw[IN * HID];
    __shared__ float sx[4][IN];
    int tx = threadIdx.x;
    for (int i = tx; i < IN * HID; i += 256) sw[i] = w[i];
    int row0 = blockIdx.x * 4;
    if (tx < 128) {
        float4 v = *(const float4*)(x + (size_t)(row0 + (tx >> 5)) * IN + (tx & 31) * 4);
        *(float4*)&sx[tx >> 5][(tx & 31) * 4] = v;
    }
    __syncthreads();
    int c = tx & 63, r = tx >> 6;
    float acc = b[c];
#pragma unroll
    for (int k = 0; k < IN; k += 4) {
        float4 xa = *(const float4*)&sx[r][k];
        acc += xa.x * sw[(k + 0) * HID + c];
        acc += xa.y * sw[(k + 1) * HID + c];
        acc += xa.z * sw[(k + 2) * HID + c];
        acc += xa.w * sw[(k + 3) * HID + c];
    }
    size_t idx = (size_t)(row0 + r) * HID + c;
    h[idx] = acc;
    float sum = acc;
    for (int o = 32; o >= 1; o >>= 1) sum += __shfl_xor(sum, o);
    float mu = sum * (1.0f / 64.0f);
    float d  = acc - mu;
    float vs = d * d;
    for (int o = 32; o >= 1; o >>= 1) vs += __shfl_xor(vs, o);
    float rr = rsqrtf(vs * (1.0f / 64.0f) + EPS);
    float zz = d * rr * g0[c] + b0[c];
    z0[idx] = f2bf(zz > 0.0f ? zz : 0.0f);
}

// ---------------------------------------------------------------------------
// Kernel 3 (per layer). EXACT r18 body (session best, 364.7 us total):
// bf16 z, packed (w|idx) single-shfl gather, branch-free padded trips,
// launch_bounds(256,8), 32-bit addressing, deferred zi/di, W from L1,
// no __syncthreads (ss wave-private).
// ---------------------------------------------------------------------------
__global__ __launch_bounds__(256, 8) void k_layer(
    float* __restrict__ h, const unsigned short* __restrict__ z_in,
    unsigned short* __restrict__ z_out,
    const int* __restrict__ ell, const int* __restrict__ cnt,
    const float* __restrict__ dinv, const float* __restrict__ w,
    const float* __restrict__ g_next, const float* __restrict__ b_next,
    float beta, int is_last,
    const float* __restrict__ head_w, const float* __restrict__ head_b,
    float* __restrict__ out) {
    __shared__ float ss[16][HID];
    int tx = threadIdx.x;
    int lane = tx & 63, wid = tx >> 6;
    int p = lane & 15, q = lane >> 4;
    int bid = blockIdx.x;
    int swz = (bid & 7) * (int)(gridDim.x >> 3) + (bid >> 3);
    int row0 = swz * 16 + wid * 4;
    int jbase = row0 & ~(N - 1);
    const ushort4* zb4 = (const ushort4*)z_in + (unsigned)jbase * 16u;
    const ushort4* zr4 = (const ushort4*)z_in;

    int nn[4];
    unsigned mypk[4];
#pragma unroll
    for (int rr = 0; rr < 4; rr++) {
        int row = row0 + rr;
        nn[rr] = cnt[row];
        mypk[rr] = 0u;
        if (lane < nn[rr]) {
            int j = ell[(unsigned)row * K_CAP + lane];
            union { float f; unsigned v; } u;
            u.f = dinv[jbase + j];
            mypk[rr] = (u.v & 0xFFFFF800u) | (unsigned)j;
        }
    }
    int ntm = 0;
#pragma unroll
    for (int rr = 0; rr < 4; rr++) {
        int nm = nn[rr] < 64 ? nn[rr] : 64;
        nm = (nm + 3) & ~3;
        ntm = nm > ntm ? nm : ntm;
    }
    float4 acc[4];
#pragma unroll
    for (int rr = 0; rr < 4; rr++) acc[rr] = make_float4(0.f, 0.f, 0.f, 0.f);
    for (int t = q; t < ntm; t += 4) {
#pragma unroll
        for (int rr = 0; rr < 4; rr++) {
            unsigned v = (unsigned)__shfl((int)mypk[rr], t);
            int j = (int)(v & 0x7FFu);
            union { unsigned u; float f; } wu; wu.u = v & 0xFFFFF800u;
            float wj = wu.f;
            ushort4 zu = zb4[(unsigned)(j * 16 + p)];
            acc[rr].x += wj * bf2f(zu.x); acc[rr].y += wj * bf2f(zu.y);
            acc[rr].z += wj * bf2f(zu.z); acc[rr].w += wj * bf2f(zu.w);
        }
    }
#pragma unroll
    for (int rr = 0; rr < 4; rr++) {
        for (int t = 64 + q; t < nn[rr]; t += 4) {
            int   j  = jbase + ell[(unsigned)(row0 + rr) * K_CAP + t];
            float wj = dinv[j];
            ushort4 zu = zr4[(unsigned)(j * 16 + p)];
            acc[rr].x += wj * bf2f(zu.x); acc[rr].y += wj * bf2f(zu.y);
            acc[rr].z += wj * bf2f(zu.z); acc[rr].w += wj * bf2f(zu.w);
        }
    }
    const float c1 = 1.0f - ALPHA;
#pragma unroll
    for (int rr = 0; rr < 4; rr++) {
        float4 a = acc[rr];
        a.x += __shfl_xor(a.x, 16); a.y += __shfl_xor(a.y, 16);
        a.z += __shfl_xor(a.z, 16); a.w += __shfl_xor(a.w, 16);
        a.x += __shfl_xor(a.x, 32); a.y += __shfl_xor(a.y, 32);
        a.z += __shfl_xor(a.z, 32); a.w += __shfl_xor(a.w, 32);
        int row = row0 + rr;
        float dd = dinv[row];
        ushort4 zu = zr4[(unsigned)(row * 16 + p)];
        float4 zi = make_float4(bf2f(zu.x), bf2f(zu.y), bf2f(zu.z), bf2f(zu.w));
        float4 s4;
        s4.x = c1 * dd * (a.x + dd * zi.x) + ALPHA * zi.x;
        s4.y = c1 * dd * (a.y + dd * zi.y) + ALPHA * zi.y;
        s4.z = c1 * dd * (a.z + dd * zi.z) + ALPHA * zi.z;
        s4.w = c1 * dd * (a.w + dd * zi.w) + ALPHA * zi.w;
        if (q == 0) *(float4*)&ss[wid * 4 + rr][4 * p] = s4;
    }
    float mv[4] = {0.f, 0.f, 0.f, 0.f};
#pragma unroll 4
    for (int k = 0; k < HID; k += 4) {
        float w0 = w[(unsigned)((k + 0) * HID + lane)];
        float w1 = w[(unsigned)((k + 1) * HID + lane)];
        float w2 = w[(unsigned)((k + 2) * HID + lane)];
        float w3 = w[(unsigned)((k + 3) * HID + lane)];
#pragma unroll
        for (int rr = 0; rr < 4; rr++) {
            float4 sk = *(const float4*)&ss[wid * 4 + rr][k];
            mv[rr] += sk.x * w0 + sk.y * w1 + sk.z * w2 + sk.w * w3;
        }
    }
#pragma unroll
    for (int rr = 0; rr < 4; rr++) {
        int row = row0 + rr;
        float s_c = ss[wid * 4 + rr][lane];
        unsigned idx = (unsigned)(row * HID + lane);
        float hn = __builtin_nontemporal_load(h + idx) +
                   (1.0f - beta) * s_c + beta * mv[rr];
        if (!is_last) {
            __builtin_nontemporal_store(hn, h + idx);
            float sum = hn;
            for (int o = 32; o >= 1; o >>= 1) sum += __shfl_xor(sum, o);
            float mu = sum * (1.0f / 64.0f);
            float d  = hn - mu;
            float vs = d * d;
            for (int o = 32; o >= 1; o >>= 1) vs += __shfl_xor(vs, o);
            float rv = rsqrtf(vs * (1.0f / 64.0f) + EPS);
            float zz = d * rv * g_next[lane] + b_next[lane];
            z_out[idx] = f2bf(zz > 0.0f ? zz : 0.0f);
        } else {
            float v = hn * head_w[lane];
            for (int o = 32; o >= 1; o >>= 1) v += __shfl_xor(v, o);
            if (lane == 0) out[row] = v + head_b[0];
        }
    }
}

extern "C" void kernel_launch(void* const* d_in, const int* in_sizes, int n_in,
                              void* d_out, int out_size, void* d_ws, size_t ws_size,
                              hipStream_t stream) {
    const float* x      = (const float*)d_in[0];
    const float* adj    = (const float*)d_in[1];
    const float* proj_w = (const float*)d_in[2];
    const float* proj_b = (const float*)d_in[3];
    const float* ln_g   = (const float*)d_in[4];
    const float* ln_b   = (const float*)d_in[5];
    const float* conv_w = (const float*)d_in[6];
    const float* head_w = (const float*)d_in[7];
    const float* head_b = (const float*)d_in[8];
    float* out = (float*)d_out;

    float* h  = (float*)d_ws;                        // ROWS*HID f32
    unsigned short* za = (unsigned short*)(h + (size_t)ROWS * HID);  // bf16
    unsigned short* zb = za + (size_t)ROWS * HID;                    // bf16
    float* dinv = (float*)(zb + (size_t)ROWS * HID); // ROWS
    int*   cnt  = (int*)(dinv + ROWS);               // ROWS
    int*   ell  = cnt + ROWS;                        // ROWS*K_CAP

    dim3 blk(256);

    k_build<<<dim3(ROWS / 4), blk, 0, stream>>>(adj, ell, cnt, dinv);
    k_proj_ln<<<dim3(ROWS / 4), blk, 0, stream>>>(x, proj_w, proj_b, ln_g, ln_b, h, za);

    unsigned short* zin = za;
    unsigned short* zout = zb;
    for (int i = 0; i < 4; i++) {
        float beta = (float)log(1.0 / (double)(i + 1) + 1.0);
        int last = (i == 3);
        int gi = (i + 1) < 3 ? (i + 1) : 3;
        k_layer<<<dim3(ROWS / 16), blk, 0, stream>>>(h, zin, zout, ell, cnt, dinv,
                                                     conv_w + (size_t)i * HID * HID,
                                                     ln_g + gi * HID, ln_b + gi * HID,
                                                     beta, last, head_w, head_b, out);
        unsigned short* t = zin; zin = zout; zout = t;
    }
}